// Round 4
// baseline (3756.073 us; speedup 1.0000x reference)
//
#include <hip/hip_runtime.h>
#include <cstdint>
#include <cstddef>

// ---------------------------------------------------------------------------
// QLSTM: LSTM scan (recurrence) + batch-axis attention quirk, all-f16 internal.
// Pipeline: prep (weight transposes/swizzles) -> cvt_x -> GEMM xproj (gate-
//           permuted epilogue) -> scan (64 WGs x 256 thr, thread t owns all 4
//           gates of unit t; 416 VGPR + 96KB LDS resident weights) ->
//           GEMM qkv -> fused per-(s,h) attention -> GEMM out_proj (+Hseq add)
// R4: no asm pins (R2/R3 container-failure suspect: 192 pinned ranges @ 256
//     budget). 1 wave/SIMD => 512-VGPR budget; remat blocked by dropping
//     __restrict__ on Wscan (in-loop global stores may alias). One barrier
//     per step via double-buffered hx.
// ws map (bytes):
//   [0, 134217728)          Xp f16 [1024][64][256u][4g] (reused: qkv@0, ctx@96M)
//   [134217728, +33554432)  Xh f16 [65536][256]
//   [167772160, +33554432)  Hseq_h f16 [65536][256]
//   [201326592, +524288)    W_scan f16 [q=32 uint4-chunks][c=1024 cols][8]
//   [201850880, +524288)    Wxt frag-major f16 (N=1024,K=256)
//   [202375168, +393216)    in_proj frag-major f16 (N=768,K=256)
//   [202768384, +131072)    out_proj frag-major f16 (N=256,K=256)
//   [202899456, +4096)      bias4 f32 [1024] (gate-major g*256+j)
// ---------------------------------------------------------------------------

typedef _Float16 f16;
typedef __attribute__((ext_vector_type(2))) _Float16 half2v;
typedef __attribute__((ext_vector_type(4))) _Float16 half4v;
typedef __attribute__((ext_vector_type(8))) _Float16 half8v;
typedef __attribute__((ext_vector_type(4))) float   float4v;

static __device__ __forceinline__ half2v u2h(unsigned u) {
  union { unsigned u; half2v h; } x; x.u = u; return x.h;
}
static __device__ __forceinline__ float sigm(float x) {
  return 1.0f / (1.0f + __expf(-x));
}
static __device__ __forceinline__ float tanh_fast(float x) {
  x = fminf(15.0f, fmaxf(-15.0f, x));
  float e = __expf(2.0f * x);
  return (e - 1.0f) / (e + 1.0f);
}
static __device__ __forceinline__ const float* selW(int g, const float* a, const float* b,
                                                    const float* c, const float* d) {
  return g == 0 ? a : (g == 1 ? b : (g == 2 ? c : d));
}

// ---------------------------------------------------------------------------
// prep: build f16 weight layouts.
//  seg0: W_scan chunk-major: flat = (q*1024 + c)*8 + e ; c = u*4+g, k = q*8+e
//        value = W_g[(256+k)*256 + u]
//  seg1: Wxt frag-major (N=1024)  seg2: in_proj (N=768)  seg3: out_proj (N=256)
//  seg4: bias4[g*256+j] = b_g[j]
// frag-major B layout: flat = ((ntile*8 + kstep)*64 + lane)*8 + j ;
//   n = ntile*16 + (lane&15); k = kstep*32 + ((lane>>4)&3)*8 + j
// ---------------------------------------------------------------------------
__global__ void prep_k(const float* __restrict__ Wf, const float* __restrict__ Wi,
                       const float* __restrict__ Wg_, const float* __restrict__ Wo,
                       const float* __restrict__ bf, const float* __restrict__ bi,
                       const float* __restrict__ bg_, const float* __restrict__ bo,
                       const float* __restrict__ inpw, const float* __restrict__ outpw,
                       f16* __restrict__ wscan, f16* __restrict__ wxt,
                       f16* __restrict__ inpj, f16* __restrict__ outpj,
                       float* __restrict__ bias4)
{
  const int total = 262144 + 262144 + 196608 + 65536 + 1024;
  for (int e = blockIdx.x * blockDim.x + threadIdx.x; e < total; e += gridDim.x * blockDim.x) {
    int x = e;
    if (x < 262144) {                 // W_scan [q][c][8]
      int q = x >> 13, rem = x & 8191, c = rem >> 3, ee = rem & 7;
      int k = q * 8 + ee, u = c >> 2, g = c & 3;
      const float* W = selW(g, Wf, Wi, Wg_, Wo);
      wscan[x] = (f16)W[(256 + k) * 256 + u];
      continue;
    }
    x -= 262144;
    if (x < 262144) {                 // Wxt frag-major (N=1024)
      int j = x & 7, lane = (x >> 3) & 63, kstep = (x >> 9) & 7, ntile = x >> 12;
      int n = ntile * 16 + (lane & 15);
      int k = kstep * 32 + ((lane >> 4) & 3) * 8 + j;
      int g = n >> 8, jj = n & 255;
      const float* W = selW(g, Wf, Wi, Wg_, Wo);
      wxt[x] = (f16)W[k * 256 + jj];
      continue;
    }
    x -= 262144;
    if (x < 196608) {                 // in_proj frag-major (N=768)
      int j = x & 7, lane = (x >> 3) & 63, kstep = (x >> 9) & 7, ntile = x >> 12;
      int n = ntile * 16 + (lane & 15);
      int k = kstep * 32 + ((lane >> 4) & 3) * 8 + j;
      inpj[x] = (f16)inpw[k * 768 + n];
      continue;
    }
    x -= 196608;
    if (x < 65536) {                  // out_proj frag-major (N=256)
      int j = x & 7, lane = (x >> 3) & 63, kstep = (x >> 9) & 7, ntile = x >> 12;
      int n = ntile * 16 + (lane & 15);
      int k = kstep * 32 + ((lane >> 4) & 3) * 8 + j;
      outpj[x] = (f16)outpw[k * 256 + n];
      continue;
    }
    x -= 65536;
    {                                 // bias4
      int g = x >> 8, j = x & 255;
      const float* bp = selW(g, bf, bi, bg_, bo);
      bias4[x] = bp[j];
    }
  }
}

// ---------------------------------------------------------------------------
__global__ void cvt_x_k(const float4v* __restrict__ X, half4v* __restrict__ Xh)
{
  int i = blockIdx.x * 256 + threadIdx.x;   // grid sized exactly: 16777216/4
  float4v v = X[i];
  half4v h;
  h.x = (f16)v.x; h.y = (f16)v.y; h.z = (f16)v.z; h.w = (f16)v.w;
  Xh[i] = h;
}

// ---------------------------------------------------------------------------
// Generic MFMA GEMM: C[65536][NTOT] = A[65536][256](f16) @ Bfrag + bias[n].
// EPI=0: store f16 plain.  EPI=1: store f16 gate-permuted (col = (n&255)*4 +
// (n>>8); requires NTOT=1024).  EPI=2: f32 accumulate-add (out_proj).
// ---------------------------------------------------------------------------
template<int NTOT, int EPI>
__global__ __launch_bounds__(256, 2) void gemm_k(const f16* __restrict__ A,
    const f16* __restrict__ Bf, const float* __restrict__ bias,
    f16* __restrict__ Oh, float* __restrict__ Of)
{
  __shared__ f16 Al[8192];            // [8 mtiles][2 ksteps][64 lanes][8]
  const int tid = threadIdx.x;
  const int lane = tid & 63;
  const int wm = (tid >> 7) & 1;
  const int wn = (tid >> 6) & 1;
  const int m0 = blockIdx.y * 128, n0 = blockIdx.x * 128;

  float4v acc[4][4];
  #pragma unroll
  for (int i = 0; i < 4; ++i)
    #pragma unroll
    for (int j = 0; j < 4; ++j) { acc[i][j].x = 0.f; acc[i][j].y = 0.f; acc[i][j].z = 0.f; acc[i][j].w = 0.f; }

  #pragma unroll 1
  for (int kc = 0; kc < 4; ++kc) {
    __syncthreads();
    #pragma unroll
    for (int p = 0; p < 4; ++p) {
      int m = p * 32 + (tid >> 3);
      int kk = (tid & 7) * 8;
      half8v v = *(const half8v*)(A + (size_t)(m0 + m) * 256 + kc * 64 + kk);
      int lt = ((kk >> 3) & 3) * 16 + (m & 15);
      *(half8v*)(Al + (((m >> 4) * 2 + (kk >> 5)) * 64 + lt) * 8) = v;
    }
    __syncthreads();
    half8v bfr[4][2], afr[4][2];
    #pragma unroll
    for (int i = 0; i < 4; ++i) {
      int NT = (n0 >> 4) + wn * 4 + i;
      #pragma unroll
      for (int ks = 0; ks < 2; ++ks)
        bfr[i][ks] = *(const half8v*)(Bf + (size_t)((NT * 8 + kc * 2 + ks) * 64 + lane) * 8);
    }
    #pragma unroll
    for (int i = 0; i < 4; ++i) {
      int MT = wm * 4 + i;
      #pragma unroll
      for (int ks = 0; ks < 2; ++ks)
        afr[i][ks] = *(const half8v*)(Al + ((MT * 2 + ks) * 64 + lane) * 8);
    }
    #pragma unroll
    for (int ks = 0; ks < 2; ++ks)
      #pragma unroll
      for (int i = 0; i < 4; ++i)
        #pragma unroll
        for (int jn = 0; jn < 4; ++jn)
          acc[i][jn] = __builtin_amdgcn_mfma_f32_16x16x32_f16(afr[i][ks], bfr[jn][ks], acc[i][jn], 0, 0, 0);
  }

  const int r0 = (lane >> 4) * 4, cn = lane & 15;
  #pragma unroll
  for (int i = 0; i < 4; ++i) {
    #pragma unroll
    for (int jn = 0; jn < 4; ++jn) {
      int n = n0 + wn * 64 + jn * 16 + cn;
      float bv = bias[n];
      int col = (EPI == 1) ? ((n & 255) * 4 + (n >> 8)) : n;
      int mb = m0 + wm * 64 + i * 16 + r0;
      #pragma unroll
      for (int r = 0; r < 4; ++r) {
        float v = acc[i][jn][r] + bv;
        size_t off = (size_t)(mb + r) * NTOT + col;
        if constexpr (EPI == 2) Of[off] = v + Of[off];
        else                    Oh[off] = (f16)v;
      }
    }
  }
}

// ---------------------------------------------------------------------------
// LSTM scan. 64 WGs (one per batch) x 256 threads; thread t owns hidden unit
// t: all 4 gate columns c = t*4+g. Per step: 4 dots (k=0..207 from VGPR
// weights, k=208..255 from LDS), thread-local f/i/g/o -> cx/hx update, write
// hx to double buffer, ONE barrier. hx reads are wave-uniform (LDS broadcast).
// Weights: 26 uint4 chunks/col in VGPR (416 regs), 6 chunks/col in LDS (96KB).
// 1 wave/SIMD (launch_bounds(256,1)) -> 512-VGPR budget, no pins needed.
// Wscan deliberately NOT __restrict__: in-loop dout/Hh stores may alias it,
// which forbids the R1 remat-into-loop pathology.
// ---------------------------------------------------------------------------
#define DOT_CHUNK(HP, W0, W1, W2, W3)                                        \
  a0 = __builtin_amdgcn_fdot2(HP[0], u2h((W0).x), a0, false);                \
  a0 = __builtin_amdgcn_fdot2(HP[1], u2h((W0).y), a0, false);                \
  a0 = __builtin_amdgcn_fdot2(HP[2], u2h((W0).z), a0, false);                \
  a0 = __builtin_amdgcn_fdot2(HP[3], u2h((W0).w), a0, false);                \
  a1 = __builtin_amdgcn_fdot2(HP[0], u2h((W1).x), a1, false);                \
  a1 = __builtin_amdgcn_fdot2(HP[1], u2h((W1).y), a1, false);                \
  a1 = __builtin_amdgcn_fdot2(HP[2], u2h((W1).z), a1, false);                \
  a1 = __builtin_amdgcn_fdot2(HP[3], u2h((W1).w), a1, false);                \
  a2 = __builtin_amdgcn_fdot2(HP[0], u2h((W2).x), a2, false);                \
  a2 = __builtin_amdgcn_fdot2(HP[1], u2h((W2).y), a2, false);                \
  a2 = __builtin_amdgcn_fdot2(HP[2], u2h((W2).z), a2, false);                \
  a2 = __builtin_amdgcn_fdot2(HP[3], u2h((W2).w), a2, false);                \
  a3 = __builtin_amdgcn_fdot2(HP[0], u2h((W3).x), a3, false);                \
  a3 = __builtin_amdgcn_fdot2(HP[1], u2h((W3).y), a3, false);                \
  a3 = __builtin_amdgcn_fdot2(HP[2], u2h((W3).z), a3, false);                \
  a3 = __builtin_amdgcn_fdot2(HP[3], u2h((W3).w), a3, false);

__global__ __launch_bounds__(256, 1)
void scan_k(const f16* __restrict__ Xp, const f16* Wscan,
            float* __restrict__ dout, f16* __restrict__ Hh)
{
  extern __shared__ char smem[];
  uint4* wtl = (uint4*)smem;                   // [j*4+g][256 u]  (96 KB)
  f16* hxbuf = (f16*)(smem + 98304);           // [2][256]
  const int tid = threadIdx.x;                 // hidden unit u
  const int b = blockIdx.x;
  const uint4* Wq = (const uint4*)Wscan;       // [q=32][c=1024]

  for (int e = tid; e < 6144; e += 256) {      // chunks q=26..31 -> LDS
    int j = e >> 10, g = (e >> 8) & 3, u = e & 255;
    wtl[e] = Wq[(26 + j) * 1024 + u * 4 + g];
  }
  uint4 wv[4][26];
  #pragma unroll
  for (int q = 0; q < 26; ++q)
    #pragma unroll
    for (int g = 0; g < 4; ++g)
      wv[g][q] = Wq[q * 1024 + tid * 4 + g];

  hxbuf[tid] = (f16)0.f;                       // buffer 0 = zeros for t=0
  float cx = 0.0f, hv = 0.0f;
  const uint2* Xp64 = (const uint2*)Xp;
  __syncthreads();

  #pragma unroll 1
  for (int t = 0; t < 1024; ++t) {
    uint2 xp = Xp64[(size_t)(t * 64 + b) * 256 + tid];   // issued early
    const f16* hx = hxbuf + (t & 1) * 256;
    float a0 = 0.f, a1 = 0.f, a2 = 0.f, a3 = 0.f;
    #pragma unroll
    for (int q = 0; q < 26; ++q) {             // k = 0..207 (VGPR weights)
      half8v h8 = *(const half8v*)(hx + q * 8);
      const half2v* hp = (const half2v*)&h8;
      DOT_CHUNK(hp, wv[0][q], wv[1][q], wv[2][q], wv[3][q]);
    }
    #pragma unroll
    for (int j = 0; j < 6; ++j) {              // k = 208..255 (LDS weights)
      half8v h8 = *(const half8v*)(hx + 208 + j * 8);
      const half2v* hp = (const half2v*)&h8;
      uint4 w0 = wtl[(j * 4 + 0) * 256 + tid];
      uint4 w1 = wtl[(j * 4 + 1) * 256 + tid];
      uint4 w2 = wtl[(j * 4 + 2) * 256 + tid];
      uint4 w3 = wtl[(j * 4 + 3) * 256 + tid];
      DOT_CHUNK(hp, w0, w1, w2, w3);
    }
    half2v x01 = u2h(xp.x), x23 = u2h(xp.y);
    float fg = sigm(a0 + (float)x01.x);
    float ig = sigm(a1 + (float)x01.y);
    float gg = tanh_fast(a2 + (float)x23.x);
    float og = sigm(a3 + (float)x23.y);
    cx = fg * cx + ig * gg;
    hv = og * tanh_fast(cx);
    hxbuf[((t + 1) & 1) * 256 + tid] = (f16)hv;
    size_t off = (size_t)(t * 64 + b) * 256 + tid;
    dout[off] = hv;
    Hh[off] = (f16)hv;
    __syncthreads();
  }
  dout[(size_t)16777216 + b * 256 + tid] = hv;            // hx
  dout[(size_t)16777216 + 16384 + b * 256 + tid] = cx;    // cx
}

// ---------------------------------------------------------------------------
// Fused batch-axis attention, one WG per (s, head). (unchanged from R1)
// ---------------------------------------------------------------------------
__global__ __launch_bounds__(256, 2) void attn_k(const f16* __restrict__ qkv,
                                                 f16* __restrict__ ctx)
{
  __shared__ f16 ql[64 * 72];
  __shared__ f16 kl[64 * 72];
  __shared__ f16 vT[64 * 72];     // transposed: [d][k_b]
  __shared__ f16 at[64 * 72];     // exp'd scores (unnormalized), [q_b][k_b]
  __shared__ float sc[64 * 69];
  __shared__ float pmx[256], psm[256], rmx[64], rsm[64];
  const int tid = threadIdx.x;
  const int s = blockIdx.x >> 2, h = blockIdx.x & 3;
  {
    const int bb = tid >> 2, i = tid & 3;
    const f16* base = qkv + (size_t)(s * 64 + bb) * 768 + h * 64 + i * 16;
    half8v q0 = *(const half8v*)(base);
    half8v q1 = *(const half8v*)(base + 8);
    *(half8v*)(ql + bb * 72 + i * 16)     = q0;
    *(half8v*)(ql + bb * 72 + i * 16 + 8) = q1;
    half8v k0 = *(const half8v*)(base + 256);
    half8v k1 = *(const half8v*)(base + 264);
    *(half8v*)(kl + bb * 72 + i * 16)     = k0;
    *(half8v*)(kl + bb * 72 + i * 16 + 8) = k1;
    half8v v0 = *(const half8v*)(base + 512);
    half8v v1 = *(const half8v*)(base + 520);
    #pragma unroll
    for (int z = 0; z < 8; ++z) {
      vT[(i * 16 + z) * 72 + bb]     = v0[z];
      vT[(i * 16 + 8 + z) * 72 + bb] = v1[z];
    }
  }
  __syncthreads();
  {
    const int qb = tid >> 2, g = tid & 3;
    half8v qr[8];
    #pragma unroll
    for (int i = 0; i < 8; ++i) qr[i] = *(const half8v*)(ql + qb * 72 + i * 8);
    #pragma unroll 1
    for (int jj = 0; jj < 16; ++jj) {
      int kb = g + jj * 4;
      float a = 0.0f;
      #pragma unroll
      for (int i = 0; i < 8; ++i) {
        half8v kr = *(const half8v*)(kl + kb * 72 + i * 8);
        const half2v* kp = (const half2v*)&kr;
        const half2v* qp = (const half2v*)&qr[i];
        #pragma unroll
        for (int z = 0; z < 4; ++z) a = __builtin_amdgcn_fdot2(qp[z], kp[z], a, false);
      }
      sc[qb * 69 + kb] = a * 0.125f;
    }
  }
  __syncthreads();
  {
    const int r = tid & 63, q = tid >> 6;
    float m = -1e30f;
    #pragma unroll
    for (int z = 0; z < 16; ++z) m = fmaxf(m, sc[r * 69 + q * 16 + z]);
    pmx[q * 64 + r] = m;
  }
  __syncthreads();
  if (tid < 64)
    rmx[tid] = fmaxf(fmaxf(pmx[tid], pmx[64 + tid]), fmaxf(pmx[128 + tid], pmx[192 + tid]));
  __syncthreads();
  {
    const int r = tid & 63, q = tid >> 6;
    float mx = rmx[r], ssum = 0.0f;
    #pragma unroll
    for (int z = 0; z < 16; ++z) {
      float e = __expf(sc[r * 69 + q * 16 + z] - mx);
      ssum += e;
      at[r * 72 + q * 16 + z] = (f16)e;
    }
    psm[q * 64 + r] = ssum;
  }
  __syncthreads();
  if (tid < 64)
    rsm[tid] = (psm[tid] + psm[64 + tid]) + (psm[128 + tid] + psm[192 + tid]);
  __syncthreads();
  {
    const int qb = tid >> 2, g = tid & 3;
    half8v ar[8];
    #pragma unroll
    for (int i = 0; i < 8; ++i) ar[i] = *(const half8v*)(at + qb * 72 + i * 8);
    const float rinv = 1.0f / rsm[qb];
    f16* outp = ctx + (size_t)(s * 64 + qb) * 256 + h * 64;
    #pragma unroll 1
    for (int z = 0; z < 16; ++z) {
      int d = g + z * 4;
      float a = 0.0f;
      #pragma unroll
      for (int i = 0; i < 8; ++i) {
        half8v vr = *(const half8v*)(vT + d * 72 + i * 8);
        const half2v* vp = (const half2v*)&vr;
        const half2v* ap = (const half2v*)&ar[i];
        #pragma unroll
        for (int zz = 0; zz < 4; ++zz) a = __builtin_amdgcn_fdot2(ap[zz], vp[zz], a, false);
      }
      outp[d] = (f16)(a * rinv);
    }
  }
}

// ---------------------------------------------------------------------------
extern "C" void kernel_launch(void* const* d_in, const int* in_sizes, int n_in,
                              void* d_out, int out_size, void* d_ws, size_t ws_size,
                              hipStream_t stream)
{
  (void)in_sizes; (void)n_in; (void)out_size; (void)ws_size;
  const float* X    = (const float*)d_in[0];
  const float* Wf   = (const float*)d_in[1];
  const float* bf   = (const float*)d_in[2];
  const float* Wi   = (const float*)d_in[3];
  const float* bi   = (const float*)d_in[4];
  const float* Wg   = (const float*)d_in[5];
  const float* bg   = (const float*)d_in[6];
  const float* Wo   = (const float*)d_in[7];
  const float* bo   = (const float*)d_in[8];
  const float* inpw = (const float*)d_in[9];
  const float* inpb = (const float*)d_in[10];
  const float* outpw= (const float*)d_in[11];
  const float* outpb= (const float*)d_in[12];

  char* ws = (char*)d_ws;
  f16*   Xp    = (f16*)(ws + 0);
  f16*   qkv   = (f16*)(ws + 0);                 // reuses Xp region after scan
  f16*   ctxh  = (f16*)(ws + 100663296);         // also inside old Xp region
  f16*   Xh    = (f16*)(ws + 134217728);
  f16*   Hh    = (f16*)(ws + 167772160);
  f16*   wscan = (f16*)(ws + 201326592);
  f16*   wxt   = (f16*)(ws + 201850880);
  f16*   inpj  = (f16*)(ws + 202375168);
  f16*   outpj = (f16*)(ws + 202768384);
  float* bias4 = (float*)(ws + 202899456);
  float* out   = (float*)d_out;

  prep_k<<<1024, 256, 0, stream>>>(Wf, Wi, Wg, Wo, bf, bi, bg, bo, inpw, outpw,
                                   wscan, wxt, inpj, outpj, bias4);
  cvt_x_k<<<16384, 256, 0, stream>>>((const float4v*)X, (half4v*)Xh);
  gemm_k<1024, 1><<<dim3(8, 512), 256, 0, stream>>>(Xh, wxt, bias4, Xp, nullptr);
  scan_k<<<64, 256, 99328, stream>>>(Xp, wscan, out, Hh);
  gemm_k<768, 0><<<dim3(6, 512), 256, 0, stream>>>(Hh, inpj, inpb, qkv, nullptr);
  attn_k<<<4096, 256, 0, stream>>>(qkv, ctxh);
  gemm_k<256, 2><<<dim3(2, 512), 256, 0, stream>>>(ctxh, outpj, outpb, nullptr, out);
}